// Round 1
// baseline (145.475 us; speedup 1.0000x reference)
//
#include <hip/hip_runtime.h>

#define NQ   10
#define NL   3
#define NAMP 1024        // 2^10 amplitudes
#define BT   128         // threads per block
// 8 amplitudes (4 gate-pairs) per thread

__global__ __launch_bounds__(BT) void qnn_kernel(const float* __restrict__ x,
                                                 const float* __restrict__ w,
                                                 float* __restrict__ out)
{
    __shared__ float2 amp[NAMP];            // state vector for this batch element
    __shared__ float  cs[NQ], sn[NQ];       // RY(x) cos/sin (batch-dependent)
    __shared__ float2 rot[NL][NQ][4];       // Rot matrices (batch-independent)
    __shared__ float  zred[2][NQ];

    const int tid = threadIdx.x;
    const int b   = blockIdx.x;

    // ---- init |0...0> ----
    for (int a = tid; a < NAMP; a += BT)
        amp[a] = make_float2(a == 0 ? 1.0f : 0.0f, 0.0f);

    // ---- RY angles for this batch element ----
    if (tid < NQ) {
        float xv = x[b * NQ + tid] * 0.5f;
        cs[tid] = cosf(xv);
        sn[tid] = sinf(xv);
    }
    // ---- Rot(phi,theta,omega) = RZ(om) RY(th) RZ(phi) matrices ----
    if (tid < NL * NQ) {
        int l = tid / NQ, q = tid % NQ;
        const float* wp = w + (l * NQ + q) * 3;
        float phi = wp[0], th = wp[1], om = wp[2];
        float ct = cosf(th * 0.5f), st = sinf(th * 0.5f);
        float ap = (phi + om) * 0.5f, am = (phi - om) * 0.5f;
        float cap = cosf(ap), sap = sinf(ap);
        float cam = cosf(am), sam = sinf(am);
        rot[l][q][0] = make_float2( cap * ct, -sap * ct);  // m00 = e^{-i(phi+om)/2} c
        rot[l][q][1] = make_float2(-cam * st, -sam * st);  // m01 = -e^{+i(phi-om)/2} s
        rot[l][q][2] = make_float2( cam * st, -sam * st);  // m10 = e^{-i(phi-om)/2} s
        rot[l][q][3] = make_float2( cap * ct,  sap * ct);  // m11 = e^{+i(phi+om)/2} c
    }
    __syncthreads();

    for (int l = 0; l < NL; ++l) {
        // ---- fused (Rot * RY) single-qubit gate on each wire ----
        #pragma unroll
        for (int q = 0; q < NQ; ++q) {
            const float c = cs[q], s = sn[q];
            const float2 R00 = rot[l][q][0], R01 = rot[l][q][1];
            const float2 R10 = rot[l][q][2], R11 = rot[l][q][3];
            // M = R * [[c,-s],[s,c]]
            const float2 m00 = make_float2( R00.x*c + R01.x*s,  R00.y*c + R01.y*s);
            const float2 m01 = make_float2(-R00.x*s + R01.x*c, -R00.y*s + R01.y*c);
            const float2 m10 = make_float2( R10.x*c + R11.x*s,  R10.y*c + R11.y*s);
            const float2 m11 = make_float2(-R10.x*s + R11.x*c, -R10.y*s + R11.y*c);
            const unsigned bit = 1u << q;
            #pragma unroll
            for (int k = 0; k < 4; ++k) {
                unsigned p  = (unsigned)tid + k * BT;                 // pair 0..511
                unsigned i0 = ((p >> q) << (q + 1)) | (p & (bit - 1));
                unsigned i1 = i0 | bit;
                float2 a0 = amp[i0], a1 = amp[i1];
                float2 n0, n1;
                n0.x = m00.x*a0.x - m00.y*a0.y + m01.x*a1.x - m01.y*a1.y;
                n0.y = m00.x*a0.y + m00.y*a0.x + m01.x*a1.y + m01.y*a1.x;
                n1.x = m10.x*a0.x - m10.y*a0.y + m11.x*a1.x - m11.y*a1.y;
                n1.y = m10.x*a0.y + m10.y*a0.x + m11.x*a1.y + m11.y*a1.x;
                amp[i0] = n0;
                amp[i1] = n1;
            }
            __syncthreads();
        }
        // ---- ring of CNOTs: control q -> target (q+1)%NQ ----
        #pragma unroll
        for (int q = 0; q < NQ; ++q) {
            const int ctl = q, tgt = (q + 1) % NQ;
            const int lo = ctl < tgt ? ctl : tgt;
            const int hi = ctl < tgt ? tgt : ctl;
            #pragma unroll
            for (int k = 0; k < 2; ++k) {
                unsigned f   = (unsigned)tid + k * BT;               // 0..255 free bits
                unsigned tmp = ((f >> lo) << (lo + 1)) | (f & ((1u << lo) - 1));
                unsigned i   = ((tmp >> hi) << (hi + 1)) | (tmp & ((1u << hi) - 1));
                i |= (1u << ctl);                                    // control = 1
                unsigned j = i | (1u << tgt);                        // target = 1
                float2 ai = amp[i], aj = amp[j];
                amp[i] = aj;
                amp[j] = ai;
            }
            __syncthreads();
        }
    }

    // ---- measurement: <Z_q> = sum_a (1 - 2*bit_q(a)) |amp_a|^2 ----
    float z[NQ];
    #pragma unroll
    for (int q = 0; q < NQ; ++q) z[q] = 0.f;
    for (int a = tid; a < NAMP; a += BT) {
        float2 v = amp[a];
        float p = v.x * v.x + v.y * v.y;
        #pragma unroll
        for (int q = 0; q < NQ; ++q)
            z[q] += ((a >> q) & 1) ? -p : p;
    }
    #pragma unroll
    for (int q = 0; q < NQ; ++q)
        for (int off = 32; off > 0; off >>= 1)
            z[q] += __shfl_xor(z[q], off, 64);

    const int wave = tid >> 6;
    const int lane = tid & 63;
    if (lane == 0)
        for (int q = 0; q < NQ; ++q) zred[wave][q] = z[q];
    __syncthreads();
    if (tid < NQ)
        out[b * NQ + tid] = zred[0][tid] + zred[1][tid];
}

extern "C" void kernel_launch(void* const* d_in, const int* in_sizes, int n_in,
                              void* d_out, int out_size, void* d_ws, size_t ws_size,
                              hipStream_t stream) {
    const float* x = (const float*)d_in[0];       // (4096, 10) f32
    const float* w = (const float*)d_in[1];       // (3, 10, 3)  f32
    float* out = (float*)d_out;                   // (4096, 10) f32
    const int B = in_sizes[0] / NQ;
    qnn_kernel<<<B, BT, 0, stream>>>(x, w, out);
}

// Round 2
// 92.915 us; speedup vs baseline: 1.5657x; 1.5657x over previous
//
#include <hip/hip_runtime.h>

#define NQ 10
#define NL 3

// ---------------- complex helpers ----------------
__device__ __forceinline__ float2 cxmul(float2 c, float2 v) {
    return make_float2(fmaf(c.x, v.x, -c.y * v.y), fmaf(c.x, v.y, c.y * v.x));
}
__device__ __forceinline__ float2 cxmad(float2 c, float2 v, float2 acc) {
    acc.x = fmaf(c.x, v.x, fmaf(-c.y, v.y, acc.x));
    acc.y = fmaf(c.x, v.y, fmaf( c.y, v.x, acc.y));
    return acc;
}
__device__ __forceinline__ float2 shxor2(float2 v, int m) {
    return make_float2(__shfl_xor(v.x, m, 64), __shfl_xor(v.y, m, 64));
}

// Generalized single-qubit gate under a GF(2) index transform.
// Pairs physical index p with p^MASK; element with parity(p&RMASK)==0 is the
// "logical 0" side. MASK/RMASK compile-time. Lane = high 6 bits, slot = low 4.
template<int MASK, int RMASK>
__device__ __forceinline__ void apply_gate(float2 (&a)[16],
        float2 m00, float2 m01, float2 m10, float2 m11, int lane)
{
    constexpr int LM = (MASK >> 4) & 63;   // lane xor mask
    constexpr int JM = MASK & 15;          // slot xor mask
    constexpr int RH = (RMASK >> 4) & 63;  // lane parity mask
    constexpr int RL = RMASK & 15;         // slot parity mask

    const int lp = (RH != 0) ? (__popc(lane & RH) & 1) : 0;
    // coefficients by slot-parity sp (total parity = lp ^ sp):
    // total==0 -> new = m00*mine + m01*other ; total==1 -> m11*mine + m10*other
    const float2 cA0 = lp ? m11 : m00, cB0 = lp ? m10 : m01;
    const float2 cA1 = lp ? m00 : m11, cB1 = lp ? m01 : m10;

    if constexpr (JM == 0) {
        #pragma unroll
        for (int j = 0; j < 16; ++j) {
            float2 other = shxor2(a[j], LM);
            const int sp = __builtin_popcount(j & RL) & 1;
            const float2 cA = sp ? cA1 : cA0, cB = sp ? cB1 : cB0;
            a[j] = cxmad(cB, other, cxmul(cA, a[j]));
        }
    } else {
        constexpr int HB = 1 << (31 - __builtin_clz((unsigned)JM));
        #pragma unroll
        for (int j = 0; j < 16; ++j) {
            if (j & HB) continue;              // orbit leaders only
            const int k = j ^ JM;
            const float2 aj = a[j], ak = a[k];
            float2 oj, ok;
            if constexpr (LM != 0) { oj = shxor2(ak, LM); ok = shxor2(aj, LM); }
            else                   { oj = ak;             ok = aj;             }
            const int spj = __builtin_popcount(j & RL) & 1;
            const int spk = __builtin_popcount(k & RL) & 1;
            const float2 cAj = spj ? cA1 : cA0, cBj = spj ? cB1 : cB0;
            const float2 cAk = spk ? cA1 : cA0, cBk = spk ? cB1 : cB0;
            a[j] = cxmad(cBj, oj, cxmul(cAj, aj));
            a[k] = cxmad(cBk, ok, cxmul(cAk, ak));
        }
    }
}

__global__ __launch_bounds__(256, 4)
void qnn_kernel(const float* __restrict__ x, const float* __restrict__ w,
                float* __restrict__ out)
{
    __shared__ float4 rotL[NL * NQ][2];   // Rot matrices: (R00,R01) | (R10,R11)

    const int t    = threadIdx.x;
    const int lane = t & 63;
    const int b    = blockIdx.x * 4 + (t >> 6);   // one wave per batch element

    // ---- 30 batch-independent Rot matrices (precise trig, once per block) ----
    if (t < NL * NQ) {
        const float* wp = w + t * 3;
        float phi = wp[0], th = wp[1], om = wp[2];
        float ct = cosf(th * 0.5f), st = sinf(th * 0.5f);
        float ap = (phi + om) * 0.5f, am = (phi - om) * 0.5f;
        float cap = cosf(ap), sap = sinf(ap);
        float cam = cosf(am), sam = sinf(am);
        rotL[t][0] = make_float4(cap * ct, -sap * ct, -cam * st, -sam * st); // R00,R01
        rotL[t][1] = make_float4(cam * st, -sam * st,  cap * ct,  sap * ct); // R10,R11
    }
    __syncthreads();

    // ---- per-batch RY angles (lanes 0..9 hold qubit's cos/sin) ----
    float myc = 0.f, mys = 0.f;
    if (lane < NQ) {
        float xv = x[b * NQ + lane] * 0.5f;
        myc = __cosf(xv);
        mys = __sinf(xv);
    }

    // ---- state |0...0>: physical index 0 = lane 0, slot 0 ----
    float2 a[16];
    #pragma unroll
    for (int j = 0; j < 16; ++j) a[j] = make_float2(0.f, 0.f);
    if (lane == 0) a[0].x = 1.f;

    // Fused gate M = Rot * RY(c,s); CNOT rings folded into compile-time masks.
#define GATE(IDX, Q, MASK, RMASK) do {                                        \
        const float4 r0 = rotL[IDX][0];                                       \
        const float4 r1 = rotL[IDX][1];                                       \
        const float cq = __shfl(myc, Q, 64);                                  \
        const float sq = __shfl(mys, Q, 64);                                  \
        const float2 g00 = make_float2(fmaf(r0.x, cq,  r0.z * sq),            \
                                       fmaf(r0.y, cq,  r0.w * sq));           \
        const float2 g01 = make_float2(fmaf(r0.z, cq, -r0.x * sq),            \
                                       fmaf(r0.w, cq, -r0.y * sq));           \
        const float2 g10 = make_float2(fmaf(r1.x, cq,  r1.z * sq),            \
                                       fmaf(r1.y, cq,  r1.w * sq));           \
        const float2 g11 = make_float2(fmaf(r1.z, cq, -r1.x * sq),            \
                                       fmaf(r1.w, cq, -r1.y * sq));           \
        apply_gate<MASK, RMASK>(a, g00, g01, g10, g11, lane);                 \
    } while (0)

    // Layer 1 (A = I)
    GATE( 0, 0, 0x001, 0x001);  GATE( 1, 1, 0x002, 0x002);
    GATE( 2, 2, 0x004, 0x004);  GATE( 3, 3, 0x008, 0x008);
    GATE( 4, 4, 0x010, 0x010);  GATE( 5, 5, 0x020, 0x020);
    GATE( 6, 6, 0x040, 0x040);  GATE( 7, 7, 0x080, 0x080);
    GATE( 8, 8, 0x100, 0x100);  GATE( 9, 9, 0x200, 0x200);
    // Layer 2 (after ring 1)
    GATE(10, 0, 0x003, 0x3FE);  GATE(11, 1, 0x006, 0x003);
    GATE(12, 2, 0x00C, 0x007);  GATE(13, 3, 0x018, 0x00F);
    GATE(14, 4, 0x030, 0x01F);  GATE(15, 5, 0x060, 0x03F);
    GATE(16, 6, 0x0C0, 0x07F);  GATE(17, 7, 0x180, 0x0FF);
    GATE(18, 8, 0x300, 0x1FF);  GATE(19, 9, 0x203, 0x3FF);
    // Layer 3 (after ring 2)
    GATE(20, 0, 0x005, 0x2AB);  GATE(21, 1, 0x00A, 0x3FD);
    GATE(22, 2, 0x014, 0x3FA);  GATE(23, 3, 0x028, 0x3F5);
    GATE(24, 4, 0x050, 0x3EA);  GATE(25, 5, 0x0A0, 0x3D5);
    GATE(26, 6, 0x140, 0x3AA);  GATE(27, 7, 0x280, 0x355);
    GATE(28, 8, 0x103, 0x2AA);  GATE(29, 9, 0x206, 0x155);
#undef GATE

    // ---- measurement: <Z_q> = sum_p (-1)^parity(p & Rf_q) |amp_p|^2 ----
    float P[16];
    #pragma unroll
    for (int j = 0; j < 16; ++j)
        P[j] = fmaf(a[j].x, a[j].x, a[j].y * a[j].y);

    float vout = 0.f;
#define MEAS(Q, RMASK) do {                                                   \
        constexpr int RH = ((RMASK) >> 4) & 63, RL = (RMASK) & 15;            \
        float v = 0.f;                                                        \
        _Pragma("unroll")                                                     \
        for (int j = 0; j < 16; ++j)                                          \
            v += (__builtin_popcount(j & RL) & 1) ? -P[j] : P[j];             \
        if (__popc(lane & RH) & 1) v = -v;                                    \
        v += __shfl_xor(v, 32, 64); v += __shfl_xor(v, 16, 64);               \
        v += __shfl_xor(v,  8, 64); v += __shfl_xor(v,  4, 64);               \
        v += __shfl_xor(v,  2, 64); v += __shfl_xor(v,  1, 64);               \
        if (lane == Q) vout = v;                                              \
    } while (0)

    MEAS(0, 0x0CD); MEAS(1, 0x156); MEAS(2, 0x2AC); MEAS(3, 0x159);
    MEAS(4, 0x2B3); MEAS(5, 0x166); MEAS(6, 0x2CC); MEAS(7, 0x199);
    MEAS(8, 0x333); MEAS(9, 0x266);
#undef MEAS

    if (lane < NQ) out[b * NQ + lane] = vout;
}

extern "C" void kernel_launch(void* const* d_in, const int* in_sizes, int n_in,
                              void* d_out, int out_size, void* d_ws, size_t ws_size,
                              hipStream_t stream) {
    const float* x = (const float*)d_in[0];   // (4096, 10) f32
    const float* w = (const float*)d_in[1];   // (3, 10, 3) f32
    float* out = (float*)d_out;               // (4096, 10) f32
    const int B = in_sizes[0] / NQ;           // 4096
    qnn_kernel<<<B / 4, 256, 0, stream>>>(x, w, out);
}

// Round 3
// 79.165 us; speedup vs baseline: 1.8376x; 1.1737x over previous
//
#include <hip/hip_runtime.h>

#define NQ 10
#define NL 3

typedef float v2f __attribute__((ext_vector_type(2)));

__device__ __forceinline__ int   f2i(float v) { union { float f; int i; } u; u.f = v; return u.i; }
__device__ __forceinline__ float i2f(int v)   { union { int i; float f; } u; u.i = v; return u.f; }

// scalar complex mul (setup only)
__device__ __forceinline__ v2f cmul(v2f a, v2f b) {
    return (v2f){ fmaf(a.x, b.x, -a.y * b.y), fmaf(a.x, b.y, a.y * b.x) };
}

// ---- VOP3P packed complex helpers. K = (coef_tp0, coef_tp1); SP (compile-time
// slot parity) picks the half via op_sel. i-variant computes c + K.sel*(i*a):
// lo = c.lo - K*a.hi ; hi = c.hi + K*a.lo  (swap+neg folded into modifiers). ----
template<int SP> __device__ __forceinline__ v2f pk_mul_sel(v2f a, v2f K) {
    v2f d;
    if constexpr (SP == 0)
        asm("v_pk_mul_f32 %0, %1, %2 op_sel:[0,0] op_sel_hi:[1,0]" : "=v"(d) : "v"(a), "v"(K));
    else
        asm("v_pk_mul_f32 %0, %1, %2 op_sel:[0,1] op_sel_hi:[1,1]" : "=v"(d) : "v"(a), "v"(K));
    return d;
}
template<int SP> __device__ __forceinline__ v2f pk_fma_sel(v2f a, v2f K, v2f c) {
    v2f d;
    if constexpr (SP == 0)
        asm("v_pk_fma_f32 %0, %1, %2, %3 op_sel:[0,0,0] op_sel_hi:[1,0,1]"
            : "=v"(d) : "v"(a), "v"(K), "v"(c));
    else
        asm("v_pk_fma_f32 %0, %1, %2, %3 op_sel:[0,1,0] op_sel_hi:[1,1,1]"
            : "=v"(d) : "v"(a), "v"(K), "v"(c));
    return d;
}
template<int SP> __device__ __forceinline__ v2f pk_fma_i_sel(v2f a, v2f K, v2f c) {
    v2f d;
    if constexpr (SP == 0)
        asm("v_pk_fma_f32 %0, %1, %2, %3 op_sel:[1,0,0] op_sel_hi:[0,0,1] neg_lo:[1,0,0]"
            : "=v"(d) : "v"(a), "v"(K), "v"(c));
    else
        asm("v_pk_fma_f32 %0, %1, %2, %3 op_sel:[1,1,0] op_sel_hi:[0,1,1] neg_lo:[1,0,0]"
            : "=v"(d) : "v"(a), "v"(K), "v"(c));
    return d;
}

// ---- lane exchange: DPP quad_perm for xor 1/2/3 (VALU pipe), ds_swizzle for
// xor<32 (no addr VALU), cached-addr ds_bpermute for xor>=32. ----
template<int LM>
__device__ __forceinline__ v2f xlane(v2f v, int baddr) {
    int x = f2i(v.x), y = f2i(v.y);
    if constexpr (LM == 1) {
        x = __builtin_amdgcn_mov_dpp(x, 177, 0xF, 0xF, false);
        y = __builtin_amdgcn_mov_dpp(y, 177, 0xF, 0xF, false);
    } else if constexpr (LM == 2) {
        x = __builtin_amdgcn_mov_dpp(x, 78, 0xF, 0xF, false);
        y = __builtin_amdgcn_mov_dpp(y, 78, 0xF, 0xF, false);
    } else if constexpr (LM == 3) {
        x = __builtin_amdgcn_mov_dpp(x, 27, 0xF, 0xF, false);
        y = __builtin_amdgcn_mov_dpp(y, 27, 0xF, 0xF, false);
    } else if constexpr (LM < 32) {
        constexpr int off = (LM << 10) | 0x1F;   // BitMode xor
        x = __builtin_amdgcn_ds_swizzle(x, off);
        y = __builtin_amdgcn_ds_swizzle(y, off);
    } else {
        x = __builtin_amdgcn_ds_bpermute(baddr, x);
        y = __builtin_amdgcn_ds_bpermute(baddr, y);
    }
    return (v2f){ i2f(x), i2f(y) };
}

// Generalized single-qubit gate under GF(2) index transform (masks verified R2).
template<int MASK, int RMASK>
__device__ __forceinline__ void apply_gate(v2f (&a)[16], float4 r0, float4 r1,
                                           float cq, float sq, int lane)
{
    constexpr int LM = (MASK >> 4) & 63;
    constexpr int JM = MASK & 15;
    constexpr int RH = (RMASK >> 4) & 63;
    constexpr int RL = RMASK & 15;

    // fuse Rot * RY(c,s)
    const float g00r = fmaf(r0.x, cq,  r0.z * sq), g00i = fmaf(r0.y, cq,  r0.w * sq);
    const float g01r = fmaf(r0.z, cq, -r0.x * sq), g01i = fmaf(r0.w, cq, -r0.y * sq);
    const float g10r = fmaf(r1.x, cq,  r1.z * sq), g10i = fmaf(r1.y, cq,  r1.w * sq);
    const float g11r = fmaf(r1.z, cq, -r1.x * sq), g11i = fmaf(r1.w, cq, -r1.y * sq);

    const int lp = (RH != 0) ? (__popc(lane & RH) & 1) : 0;
    const v2f KAr = lp ? (v2f){g11r, g00r} : (v2f){g00r, g11r};
    const v2f KAi = lp ? (v2f){g11i, g00i} : (v2f){g00i, g11i};
    const v2f KBr = lp ? (v2f){g10r, g01r} : (v2f){g01r, g10r};
    const v2f KBi = lp ? (v2f){g10i, g01i} : (v2f){g01i, g10i};

    const int baddr = ((lane ^ LM) << 2);

    if constexpr (JM == 0) {
#define QNN_X(J)                                                              \
        { constexpr int SP_ = __builtin_popcount((J) & RL) & 1;               \
          v2f o_ = xlane<LM>(a[J], baddr);                                    \
          v2f t_ = pk_mul_sel<SP_>(a[J], KAr);                                \
          t_ = pk_fma_i_sel<SP_>(a[J], KAi, t_);                              \
          t_ = pk_fma_sel<SP_>(o_, KBr, t_);                                  \
          t_ = pk_fma_i_sel<SP_>(o_, KBi, t_);                                \
          a[J] = t_; }
        QNN_X(0) QNN_X(1) QNN_X(2) QNN_X(3) QNN_X(4) QNN_X(5) QNN_X(6) QNN_X(7)
        QNN_X(8) QNN_X(9) QNN_X(10) QNN_X(11) QNN_X(12) QNN_X(13) QNN_X(14) QNN_X(15)
#undef QNN_X
    } else {
        constexpr int HB = 1 << (31 - __builtin_clz((unsigned)JM));
#define QNN_P(J)                                                              \
        if constexpr (((J) & HB) == 0) {                                      \
            constexpr int K_  = (J) ^ JM;                                     \
            constexpr int SPJ = __builtin_popcount((J) & RL) & 1;             \
            constexpr int SPK = __builtin_popcount(K_  & RL) & 1;             \
            v2f aj_ = a[J], ak_ = a[K_];                                      \
            v2f oj_, ok_;                                                     \
            if constexpr (LM != 0) { oj_ = xlane<LM>(ak_, baddr);             \
                                     ok_ = xlane<LM>(aj_, baddr); }           \
            else                   { oj_ = ak_; ok_ = aj_; }                  \
            { v2f t_ = pk_mul_sel<SPJ>(aj_, KAr);                             \
              t_ = pk_fma_i_sel<SPJ>(aj_, KAi, t_);                           \
              t_ = pk_fma_sel<SPJ>(oj_, KBr, t_);                             \
              t_ = pk_fma_i_sel<SPJ>(oj_, KBi, t_);  a[J]  = t_; }            \
            { v2f t_ = pk_mul_sel<SPK>(ak_, KAr);                             \
              t_ = pk_fma_i_sel<SPK>(ak_, KAi, t_);                           \
              t_ = pk_fma_sel<SPK>(ok_, KBr, t_);                             \
              t_ = pk_fma_i_sel<SPK>(ok_, KBi, t_);  a[K_] = t_; }            \
        }
        QNN_P(0) QNN_P(1) QNN_P(2) QNN_P(3) QNN_P(4) QNN_P(5) QNN_P(6) QNN_P(7)
        QNN_P(8) QNN_P(9) QNN_P(10) QNN_P(11) QNN_P(12) QNN_P(13) QNN_P(14) QNN_P(15)
#undef QNN_P
    }
}

__global__ __launch_bounds__(256, 4)
void qnn_kernel(const float* __restrict__ x, const float* __restrict__ w,
                float* __restrict__ out)
{
    __shared__ float4 rotL[NL * NQ][2];   // (R00,R01) | (R10,R11)

    const int t    = threadIdx.x;
    const int lane = t & 63;
    const int b    = blockIdx.x * 4 + (t >> 6);   // one wave per batch element

    if (t < NL * NQ) {
        const float* wp = w + t * 3;
        float phi = wp[0], th = wp[1], om = wp[2];
        float ct = cosf(th * 0.5f), st = sinf(th * 0.5f);
        float ap = (phi + om) * 0.5f, am = (phi - om) * 0.5f;
        float cap = cosf(ap), sap = sinf(ap);
        float cam = cosf(am), sam = sinf(am);
        rotL[t][0] = make_float4(cap * ct, -sap * ct, -cam * st, -sam * st);
        rotL[t][1] = make_float4(cam * st, -sam * st,  cap * ct,  sap * ct);
    }
    __syncthreads();

    // ---- per-batch RY cos/sin, all 10 in every lane (scalar x loads) ----
    const float* xb = x + (size_t)__builtin_amdgcn_readfirstlane(b * NQ);
    float c_[NQ], s_[NQ];
    #pragma unroll
    for (int q = 0; q < NQ; ++q) {
        float xv = xb[q] * 0.5f;
        c_[q] = __cosf(xv);
        s_[q] = __sinf(xv);
    }

    // ---- layer 1 analytic: product state amp[p] = prod_q col0(G_q)[bit_q(p)] ----
    v2f c0[4], c1[4];          // slot qubits 0..3 (col-0 coefficients)
    v2f Ln = {1.f, 0.f};       // lane-bit product (qubits 4..9)
    #pragma unroll
    for (int q = 0; q < NQ; ++q) {
        float4 r0 = rotL[q][0], r1 = rotL[q][1];
        float cq = c_[q], sq = s_[q];
        v2f g0 = { fmaf(r0.x, cq, r0.z * sq), fmaf(r0.y, cq, r0.w * sq) };
        v2f g1 = { fmaf(r1.x, cq, r1.z * sq), fmaf(r1.y, cq, r1.w * sq) };
        if (q < 4) { c0[q] = g0; c1[q] = g1; }
        else {
            v2f gg = ((lane >> (q - 4)) & 1) ? g1 : g0;
            Ln = (q == 4) ? gg : cmul(Ln, gg);
        }
    }
    v2f S01[4], SH[4];
    #pragma unroll
    for (int j = 0; j < 4; ++j)
        S01[j] = cmul((j & 1) ? c1[0] : c0[0], (j & 2) ? c1[1] : c0[1]);
    #pragma unroll
    for (int h = 0; h < 4; ++h)
        SH[h] = cmul(cmul((h & 1) ? c1[2] : c0[2], (h & 2) ? c1[3] : c0[3]), Ln);
    v2f a[16];
    #pragma unroll
    for (int j = 0; j < 16; ++j)
        a[j] = cmul(S01[j & 3], SH[j >> 2]);

    // ---- layers 2..3 (masks + parities verified in R2 kernel) ----
#define GATE(IDX, Q, MASK, RMASK) \
    apply_gate<MASK, RMASK>(a, rotL[IDX][0], rotL[IDX][1], c_[Q], s_[Q], lane);
    GATE(10, 0, 0x003, 0x3FE)  GATE(11, 1, 0x006, 0x003)
    GATE(12, 2, 0x00C, 0x007)  GATE(13, 3, 0x018, 0x00F)
    GATE(14, 4, 0x030, 0x01F)  GATE(15, 5, 0x060, 0x03F)
    GATE(16, 6, 0x0C0, 0x07F)  GATE(17, 7, 0x180, 0x0FF)
    GATE(18, 8, 0x300, 0x1FF)  GATE(19, 9, 0x203, 0x3FF)
    GATE(20, 0, 0x005, 0x2AB)  GATE(21, 1, 0x00A, 0x3FD)
    GATE(22, 2, 0x014, 0x3FA)  GATE(23, 3, 0x028, 0x3F5)
    GATE(24, 4, 0x050, 0x3EA)  GATE(25, 5, 0x0A0, 0x3D5)
    GATE(26, 6, 0x140, 0x3AA)  GATE(27, 7, 0x280, 0x355)
    GATE(28, 8, 0x103, 0x2AA)  GATE(29, 9, 0x206, 0x155)
#undef GATE

    // ---- probabilities + 4-bit Walsh-Hadamard over slots ----
    float P[16];
    #pragma unroll
    for (int j = 0; j < 16; ++j)
        P[j] = fmaf(a[j].x, a[j].x, a[j].y * a[j].y);
    #pragma unroll
    for (int bit = 0; bit < 4; ++bit) {
        #pragma unroll
        for (int j = 0; j < 16; ++j)
            if (!(j & (1 << bit))) {
                int k = j | (1 << bit);
                float u = P[j], v = P[k];
                P[j] = u + v;
                P[k] = u - v;
            }
    }

    const int bp32 = ((lane ^ 32) << 2);
    float vout = 0.f;
#define MEAS(Q, RM)                                                           \
    { constexpr int RH_ = ((RM) >> 4) & 63;                                   \
      constexpr int RL_ = (RM) & 15;                                          \
      float v = P[RL_];                                                       \
      if (__popc(lane & RH_) & 1) v = -v;                                     \
      v += i2f(__builtin_amdgcn_mov_dpp(f2i(v), 177, 0xF, 0xF, false));       \
      v += i2f(__builtin_amdgcn_mov_dpp(f2i(v), 78, 0xF, 0xF, false));        \
      v += i2f(__builtin_amdgcn_ds_swizzle(f2i(v), (4 << 10) | 0x1F));        \
      v += i2f(__builtin_amdgcn_ds_swizzle(f2i(v), (8 << 10) | 0x1F));        \
      v += i2f(__builtin_amdgcn_ds_swizzle(f2i(v), (16 << 10) | 0x1F));       \
      v += i2f(__builtin_amdgcn_ds_bpermute(bp32, f2i(v)));                   \
      if (lane == (Q)) vout = v; }
    MEAS(0, 0x0CD) MEAS(1, 0x156) MEAS(2, 0x2AC) MEAS(3, 0x159)
    MEAS(4, 0x2B3) MEAS(5, 0x166) MEAS(6, 0x2CC) MEAS(7, 0x199)
    MEAS(8, 0x333) MEAS(9, 0x266)
#undef MEAS

    if (lane < NQ) out[b * NQ + lane] = vout;
}

extern "C" void kernel_launch(void* const* d_in, const int* in_sizes, int n_in,
                              void* d_out, int out_size, void* d_ws, size_t ws_size,
                              hipStream_t stream) {
    const float* x = (const float*)d_in[0];   // (4096, 10) f32
    const float* w = (const float*)d_in[1];   // (3, 10, 3) f32
    float* out = (float*)d_out;               // (4096, 10) f32
    const int B = in_sizes[0] / NQ;           // 4096
    qnn_kernel<<<B / 4, 256, 0, stream>>>(x, w, out);
}